// Round 17
// baseline (833.961 us; speedup 1.0000x reference)
//
#include <hip/hip_runtime.h>
#include <stdint.h>

// Net_11587821765063: sequential SNN scan, T=1000 steps.
// Output = spike_out (T,1,COUT) float32 only.
//
// Round 36 (session r16): RESUBMIT of r35 (container-level infra failure,
// not a kernel result). Overrun ruled out: r29's 12.4MB float tier ran on
// this harness -> ws_size >= 12.4MB >> this 6.27MB layout. Source re-audited
// clean; protocol byte-identical to passing r34. Per the r0->r2 precedent
// (flake -> resubmit passed), measuring the plane-decode experiment:
//   r34 champion (651us dispatch) + BYTE-PLANE DECODE: x/p stored as
//   separate byte planes (p as VALUE 0-2) -> decode = one v_cvt_f32_ubyteN
//   per element (26 insts vs 52; values identical).
// Everything else verbatim r34: full-merge fast path (weq && memA==memB &&
// psA==psB -> 2 hypotheses, no collapse, pre-resolve updates), slow path
// r28, protocol (publish 0xB0|hb @8B stride, scan8w, retry, selfdec,
// d1 gated gather prefetch), epilogue. Narrow fallback: r24 verbatim.

#define T_STEPS 1000
#define CIN     784
#define COUT    512
#define CPL     13            // columns per lane (64*13 = 832 >= 784)
#define VTHR_F   12500.0f
#define PROHIB_F 11250.0f

// narrow (proven) layout
#define N_NROW        512                     // 1B per row per step
#define N_CODE_OFFSET 524288                  // 512 KiB >= 512000 B of slots
// wide slots layout (proven r24/r28): 8B per row per step
#define W_ROWBYTES    4096                    // 512 rows * 8B stride
#define CODE_BYTES    (T_STEPS * 64 * 16)     // 1,024,000 B
// plane layout: slots @0 (4MiB), codeX @4MiB, codeP @5MiB
#define P_CODEX_OFFSET 4194304
#define P_CODEP_OFFSET 5242880
#define P_TOTAL        ((size_t)P_CODEP_OFFSET + (size_t)CODE_BYTES) // 6,266,880

// ---- prep kernels ----
template <int MODE>   // 2 = plane (wide slots), 0 = narrow packed
__global__ __launch_bounds__(256) void prep_kernel(const int* __restrict__ x,
                                                   uint8_t* __restrict__ codeA,
                                                   uint8_t* __restrict__ codeB,
                                                   uint8_t* __restrict__ slots) {
    int gid = blockIdx.x * blockDim.x + threadIdx.x;   // one per (t, lane)
    if (gid >= T_STEPS * 64) return;
    if constexpr (MODE >= 1) {
        uint4 z = make_uint4(0u, 0u, 0u, 0u);
        uint4* s4 = (uint4*)slots;                      // 64000 x 64B = 4.096MB
        #pragma unroll
        for (int k = 0; k < 4; ++k) s4[(size_t)gid * 4 + k] = z;
    } else {
        ((uint2*)slots)[gid] = make_uint2(0u, 0u);      // 64000 x 8B
    }
    int t = gid >> 6;
    int lane = gid & 63;
    if constexpr (MODE == 2) {
        uint32_t wx[4] = {0u, 0u, 0u, 0u};
        uint32_t wp[4] = {0u, 0u, 0u, 0u};
        #pragma unroll
        for (int j = 0; j < CPL; ++j) {
            int col = lane * CPL + j;
            if (col < CIN) {
                int xc = x[t * CIN + col];
                int xp = (t > 0) ? x[(t - 1) * CIN + col] : 0;
                int p = xc ? 2 : ((t == 0) ? 1 : (xp ? 1 : 0));
                wx[j >> 2] |= (uint32_t)(xc & 1) << ((j & 3) * 8);
                wp[j >> 2] |= (uint32_t)p << ((j & 3) * 8);
            }
        }
        ((uint4*)codeA)[gid] = make_uint4(wx[0], wx[1], wx[2], wx[3]);
        ((uint4*)codeB)[gid] = make_uint4(wp[0], wp[1], wp[2], wp[3]);
    } else {
        uint32_t wds[4] = {0u, 0u, 0u, 0u};
        #pragma unroll
        for (int j = 0; j < CPL; ++j) {
            int col = lane * CPL + j;
            uint32_t b = 0u;
            if (col < CIN) {
                int xc = x[t * CIN + col];
                int xp = (t > 0) ? x[(t - 1) * CIN + col] : 0;
                int p = xc ? 2 : ((t == 0) ? 1 : (xp ? 1 : 0));
                b = (uint32_t)((xc & 1) | (p << 1));
            }
            wds[j >> 2] |= b << ((j & 3) * 8);
        }
        ((uint4*)codeA)[gid] = make_uint4(wds[0], wds[1], wds[2], wds[3]);
    }
}

// narrow scan: 8 row-bytes in one ull
__device__ __forceinline__ void scan8(unsigned long long gv, int kk,
                                      bool& anyset, bool& allp) {
    anyset = false; allp = true;
    #pragma unroll
    for (int i = 0; i < 8; ++i) {
        uint32_t b = (uint32_t)(gv >> (8 * i)) & 0xFFu;
        bool p = (b & 0xF0u) == 0xB0u;
        allp = allp && p;
        anyset = anyset || (p && (((b >> kk) & 1u) != 0u));
    }
}

// wide scan: 8 slots (8B stride), row byte is byte0 of each ull.
__device__ __forceinline__ void scan8w(const unsigned long long* g, int kk,
                                       bool& anyset, bool& allp) {
    anyset = false; allp = true;
    #pragma unroll
    for (int i = 0; i < 8; ++i) {
        uint32_t b = (uint32_t)(g[i] & 0xFFu);
        bool p = (b & 0xF0u) == 0xB0u;
        allp = allp && p;
        anyset = anyset || (p && (((b >> kk) & 1u) != 0u));
    }
}

// packed-byte decode (r27, narrow path)
__device__ __forceinline__ void decode_code(const uint4& c, float* xf, float* pf) {
    uint32_t cwd[4] = {c.x, c.y, c.z, c.w};
    #pragma unroll
    for (int j = 0; j < CPL; ++j) {
        xf[j] = (float)((cwd[j >> 2] >> ((j & 3) * 8)) & 1u);
        pf[j] = (float)((cwd[j >> 2] >> ((j & 3) * 8 + 1)) & 0x7Fu);
    }
}

// byte-plane decode: one v_cvt_f32_ubyteN per element (values identical:
// x in {0,1}, p in {0,1,2} stored as full bytes).
__device__ __forceinline__ void decode_planes(const uint4& cx, const uint4& cp,
                                              float* xf, float* pf) {
    uint32_t wx[4] = {cx.x, cx.y, cx.z, cx.w};
    uint32_t wp[4] = {cp.x, cp.y, cp.z, cp.w};
    #pragma unroll
    for (int j = 0; j < CPL; ++j) {
        xf[j] = (float)((wx[j >> 2] >> ((j & 3) * 8)) & 0xFFu);
        pf[j] = (float)((wp[j >> 2] >> ((j & 3) * 8)) & 0xFFu);
    }
}

// ---- fast bit-exact butterfly building blocks ----
typedef unsigned uint2ev __attribute__((ext_vector_type(2)));

__device__ __forceinline__ float pl32_sum(float v) {
    unsigned a = __builtin_bit_cast(unsigned, v);
    unsigned b = a;
#if __has_builtin(__builtin_amdgcn_permlane32_swap)
    uint2ev r = __builtin_amdgcn_permlane32_swap(a, b, false, false);
    a = r.x; b = r.y;
#else
    asm volatile("v_permlane32_swap_b32 %0, %1" : "+v"(a), "+v"(b));
#endif
    return __builtin_bit_cast(float, a) + __builtin_bit_cast(float, b);
}

__device__ __forceinline__ float pl16_sum(float v) {
    unsigned a = __builtin_bit_cast(unsigned, v);
    unsigned b = a;
#if __has_builtin(__builtin_amdgcn_permlane16_swap)
    uint2ev r = __builtin_amdgcn_permlane16_swap(a, b, false, false);
    a = r.x; b = r.y;
#else
    asm volatile("v_permlane16_swap_b32 %0, %1" : "+v"(a), "+v"(b));
#endif
    return __builtin_bit_cast(float, a) + __builtin_bit_cast(float, b);
}

template <int CTRL>
__device__ __forceinline__ float dpp_xor_sum(float v) {
    int xi = __builtin_bit_cast(int, v);
    int t = __builtin_amdgcn_update_dpp(xi, xi, CTRL, 0xF, 0xF, false);
    return v + __builtin_bit_cast(float, t);
}

// stage 4 (xor4 within 16-lane rows) in pure DPP (validated r23)
__device__ __forceinline__ float dpp_xor4_sum(float v) {
    int xi = __builtin_bit_cast(int, v);
    int t1 = __builtin_amdgcn_update_dpp(xi, xi, 0x124, 0xF, 0x5, false);
    int t2 = __builtin_amdgcn_update_dpp(t1, xi, 0x12C, 0xF, 0xA, false);
    return v + __builtin_bit_cast(float, t2);
}

// full 64-lane sum, pairing bit-identical to the validated xor butterfly
__device__ __forceinline__ float wave_sum(float v) {
    v = pl32_sum(v);                  // stage 32
    v = pl16_sum(v);                  // stage 16
    v = dpp_xor_sum<0x128>(v);        // stage 8
    v = dpp_xor4_sum(v);              // stage 4
    v = dpp_xor_sum<0x4E>(v);         // stage 2
    v = dpp_xor_sum<0xB1>(v);         // stage 1
    return v;
}

__device__ __forceinline__ int rfl(bool b) {
    return __builtin_amdgcn_readfirstlane((int)b);
}

// ======================= plane step (r34 + plane decode) ===========
__device__ __forceinline__ void snn_step_p(
    int u, int row, int lane,
    const uint4* __restrict__ codeX4, const uint4* __restrict__ codeP4,
    uint8_t* __restrict__ slots,
    float (&wA)[CPL], float (&wB)[CPL],
    float (&xfc)[CPL], float (&pfc)[CPL],
    float (&xfn)[CPL], float (&pfn)[CPL],
    uint4& cwxn, uint4& cwpn, uint4& cwxl, uint4& cwpl,
    unsigned long long (&gcur)[8], unsigned long long (&gnxt)[8],
    float& memA, float& memB, bool& psA, bool& psB,
    int& p2, int& p3, int& hb_m1, int& hb_m2,
    bool& weq, uint32_t& myb)
{
    // ---- top-of-step: plane loads for u+2; selfdec from own history ----
    if (u + 2 < T_STEPS) {
        cwxl = codeX4[(size_t)(u + 2) * 64 + lane];
        cwpl = codeP4[(size_t)(u + 2) * 64 + lane];
    } else {
        cwxl = make_uint4(0u, 0u, 0u, 0u);
        cwpl = make_uint4(0u, 0u, 0u, 0u);
    }
    const int kk = (p3 << 1) | p2;
    const bool selfdec = (u >= 2) && (((hb_m2 >> kk) & 1) != 0);
    const unsigned long long* gl =
        (const unsigned long long*)(slots + (size_t)(u >= 2 ? u - 2 : 0) * W_ROWBYTES);
    // gather for this step was PREFETCHED into gcur at end of step u-1.

    // ---- full-merge fast path (verbatim r34 logic) ----
    const bool fastc = weq && (memA == memB) && (psA == psB);
    if (rfl(fastc)) {
        float dA = 0.0f;
        #pragma unroll
        for (int j = 0; j < CPL; ++j) dA += xfc[j] * wA[j];
        float dotA = wave_sum(dA);

        decode_planes(cwxn, cwpn, xfn, pfn);

        float sa = memA + dotA;
        float m00 = fmaxf(sa, 0.0f), m01 = fmaxf(sa - PROHIB_F, 0.0f);
        bool s00 = m00 >= VTHR_F, s01 = m01 >= VTHR_F;
        int hb = (s00 ? 5 : 0) | (s01 ? 10 : 0);   // s10==s00, s11==s01

        if (lane == 0)
            __hip_atomic_store(&slots[(size_t)u * W_ROWBYTES + (size_t)row * 8],
                               (uint8_t)(0xB0u | (uint32_t)hb),
                               __ATOMIC_RELAXED, __HIP_MEMORY_SCOPE_AGENT);

        bool sprv = psA;
        if (u >= 1) {
            int v = u - 1;
            if ((v & 63) == lane) myb |= (sprv ? 1u : 0u) << (v >> 6);
        }
        memA = s00 ? 0.0f : m00;
        memB = s01 ? 0.0f : m01;

        const bool sc_eq = (s00 == s01);
        if (rfl(sc_eq)) {
            if (rfl(s00)) {                       // spike
                #pragma unroll
                for (int j = 0; j < CPL; ++j)
                    wA[j] = fminf(pfc[j] + wA[j], 127.0f);
            } else if (rfl(sprv)) {               // depression
                #pragma unroll
                for (int j = 0; j < CPL; ++j)
                    wA[j] = fmaxf(wA[j] - xfc[j], 0.0f);
            }                                     // else: unchanged
        } else {
            float s0f = s00 ? 1.0f : 0.0f;
            float s1f = s01 ? 1.0f : 0.0f;
            float d0f = (!s00 && sprv) ? 1.0f : 0.0f;
            float d1f = (!s01 && sprv) ? 1.0f : 0.0f;
            #pragma unroll
            for (int j = 0; j < CPL; ++j) {
                float base = wA[j];
                float ta = fminf(fmaf(s0f, pfc[j], base), 127.0f);
                wA[j] = fmaxf(fmaf(-d0f, xfc[j], ta), 0.0f);
                float tb = fminf(fmaf(s1f, pfc[j], base), 127.0f);
                wB[j] = fmaxf(fmaf(-d1f, xfc[j], tb), 0.0f);
            }
        }
        weq = sc_eq;
        psA = s00; psB = s01;

        // resolve bst -- feeds ONLY p2/p3 history (verbatim protocol)
        int bst = 0;
        if (u >= 2) {
            if (selfdec) {
                bst = 1;
            } else {
                bool anyset, allp;
                scan8w(gcur, kk, anyset, allp);
                if (__any((int)anyset)) { bst = 1; }
                else if (__all((int)allp)) { bst = 0; }
                else {
                    for (;;) {
                        __builtin_amdgcn_s_sleep(1);
                        #pragma unroll
                        for (int i = 0; i < 8; ++i)
                            gcur[i] = __hip_atomic_load(&gl[8 * lane + i],
                                                        __ATOMIC_RELAXED,
                                                        __HIP_MEMORY_SCOPE_AGENT);
                        scan8w(gcur, kk, anyset, allp);
                        if (__any((int)anyset)) { bst = 1; break; }
                        if (__all((int)allp)) { bst = 0; break; }
                    }
                }
            }
        }
        p3 = p2; p2 = bst;
        hb_m2 = hb_m1; hb_m1 = hb;

        if (u + 1 < T_STEPS && u >= 1) {
            const int kk2 = (p3 << 1) | p2;
            if (((hb_m2 >> kk2) & 1) == 0) {
                const unsigned long long* glp =
                    (const unsigned long long*)(slots + (size_t)(u - 1) * W_ROWBYTES);
                #pragma unroll
                for (int i = 0; i < 8; ++i)
                    gnxt[i] = __hip_atomic_load(&glp[8 * lane + i],
                                                __ATOMIC_RELAXED,
                                                __HIP_MEMORY_SCOPE_AGENT);
            }
        }
        return;
    }

    // ======================= slow path: r28 verbatim =======================
    float dotA, dotB;
    if (rfl(weq)) {
        float dA = 0.0f;
        #pragma unroll
        for (int j = 0; j < CPL; ++j) dA += xfc[j] * wA[j];
        dotA = wave_sum(dA);
        dotB = dotA;                   // bitwise-identical
    } else {
        float dA = 0.0f, dB = 0.0f;
        #pragma unroll
        for (int j = 0; j < CPL; ++j) {
            dA += xfc[j] * wA[j];
            dB += xfc[j] * wB[j];
        }
        dotA = wave_sum(dA);
        dotB = wave_sum(dB);
    }

    decode_planes(cwxn, cwpn, xfn, pfn);

    float sa = memA + dotA;
    float sb = memB + dotB;
    float m00 = fmaxf(sa, 0.0f), m01 = fmaxf(sa - PROHIB_F, 0.0f);
    float m10 = fmaxf(sb, 0.0f), m11 = fmaxf(sb - PROHIB_F, 0.0f);
    bool s00 = m00 >= VTHR_F, s01 = m01 >= VTHR_F;
    bool s10 = m10 >= VTHR_F, s11 = m11 >= VTHR_F;
    int hb = (s00 ? 1 : 0) | (s01 ? 2 : 0) | (s10 ? 4 : 0) | (s11 ? 8 : 0);

    if (lane == 0)
        __hip_atomic_store(&slots[(size_t)u * W_ROWBYTES + (size_t)row * 8],
                           (uint8_t)(0xB0u | (uint32_t)hb),
                           __ATOMIC_RELAXED, __HIP_MEMORY_SCOPE_AGENT);

    int bst = 0;
    if (u >= 2) {
        if (selfdec) {
            bst = 1;
        } else {
            bool anyset, allp;
            scan8w(gcur, kk, anyset, allp);
            if (__any((int)anyset)) { bst = 1; }
            else if (__all((int)allp)) { bst = 0; }
            else {
                for (;;) {
                    __builtin_amdgcn_s_sleep(1);       // backoff (rare path)
                    #pragma unroll
                    for (int i = 0; i < 8; ++i)
                        gcur[i] = __hip_atomic_load(&gl[8 * lane + i],
                                                    __ATOMIC_RELAXED,
                                                    __HIP_MEMORY_SCOPE_AGENT);
                    scan8w(gcur, kk, anyset, allp);
                    if (__any((int)anyset)) { bst = 1; break; }
                    if (__all((int)allp)) { bst = 0; break; }
                }
            }
        }
    }
    p3 = p2; p2 = bst;
    hb_m2 = hb_m1; hb_m1 = hb;

    bool sprv = bst ? psB : psA;
    bool sc0  = bst ? s10 : s00;
    bool sc1  = bst ? s11 : s01;
    float mc0 = bst ? m10 : m00;
    float mc1 = bst ? m11 : m01;

    if (u >= 1) {
        int v = u - 1;
        if ((v & 63) == lane) myb |= (sprv ? 1u : 0u) << (v >> 6);
    }

    memA = sc0 ? 0.0f : mc0;
    memB = sc1 ? 0.0f : mc1;

    const bool sc_eq = (sc0 == sc1);
    if (rfl(weq)) {
        if (rfl(sc_eq)) {
            if (rfl(sc0)) {                       // spike
                #pragma unroll
                for (int j = 0; j < CPL; ++j)
                    wA[j] = fminf(pfc[j] + wA[j], 127.0f);
            } else if (rfl(sprv)) {               // depression
                #pragma unroll
                for (int j = 0; j < CPL; ++j)
                    wA[j] = fmaxf(wA[j] - xfc[j], 0.0f);
            }                                     // else: unchanged
        } else {
            float s0f = sc0 ? 1.0f : 0.0f;
            float s1f = sc1 ? 1.0f : 0.0f;
            float d0f = (!sc0 && sprv) ? 1.0f : 0.0f;
            float d1f = (!sc1 && sprv) ? 1.0f : 0.0f;
            #pragma unroll
            for (int j = 0; j < CPL; ++j) {
                float base = wA[j];
                float ta = fminf(fmaf(s0f, pfc[j], base), 127.0f);
                wA[j] = fmaxf(fmaf(-d0f, xfc[j], ta), 0.0f);
                float tb = fminf(fmaf(s1f, pfc[j], base), 127.0f);
                wB[j] = fmaxf(fmaf(-d1f, xfc[j], tb), 0.0f);
            }
        }
    } else {
        if (rfl(sc_eq)) {
            if (rfl(bst != 0)) {
                if (rfl(sc0)) {
                    #pragma unroll
                    for (int j = 0; j < CPL; ++j)
                        wA[j] = fminf(pfc[j] + wB[j], 127.0f);
                } else if (rfl(sprv)) {
                    #pragma unroll
                    for (int j = 0; j < CPL; ++j)
                        wA[j] = fmaxf(wB[j] - xfc[j], 0.0f);
                } else {
                    #pragma unroll
                    for (int j = 0; j < CPL; ++j)
                        wA[j] = wB[j];
                }
            } else {
                if (rfl(sc0)) {
                    #pragma unroll
                    for (int j = 0; j < CPL; ++j)
                        wA[j] = fminf(pfc[j] + wA[j], 127.0f);
                } else if (rfl(sprv)) {
                    #pragma unroll
                    for (int j = 0; j < CPL; ++j)
                        wA[j] = fmaxf(wA[j] - xfc[j], 0.0f);
                }                                 // else: unchanged
            }
        } else {
            float s0f = sc0 ? 1.0f : 0.0f;
            float s1f = sc1 ? 1.0f : 0.0f;
            float d0f = (!sc0 && sprv) ? 1.0f : 0.0f;
            float d1f = (!sc1 && sprv) ? 1.0f : 0.0f;
            if (rfl(bst != 0)) {
                #pragma unroll
                for (int j = 0; j < CPL; ++j) {
                    float base = wB[j];
                    float ta = fminf(fmaf(s0f, pfc[j], base), 127.0f);
                    wA[j] = fmaxf(fmaf(-d0f, xfc[j], ta), 0.0f);
                    float tb = fminf(fmaf(s1f, pfc[j], base), 127.0f);
                    wB[j] = fmaxf(fmaf(-d1f, xfc[j], tb), 0.0f);
                }
            } else {
                #pragma unroll
                for (int j = 0; j < CPL; ++j) {
                    float base = wA[j];
                    float ta = fminf(fmaf(s0f, pfc[j], base), 127.0f);
                    wA[j] = fmaxf(fmaf(-d0f, xfc[j], ta), 0.0f);
                    float tb = fminf(fmaf(s1f, pfc[j], base), 127.0f);
                    wB[j] = fmaxf(fmaf(-d1f, xfc[j], tb), 0.0f);
                }
            }
        }
    }
    weq = sc_eq;
    psA = sc0; psB = sc1;

    if (u + 1 < T_STEPS && u >= 1) {          // (u+1) >= 2
        const int kk2 = (p3 << 1) | p2;
        if (((hb_m2 >> kk2) & 1) == 0) {
            const unsigned long long* glp =
                (const unsigned long long*)(slots + (size_t)(u - 1) * W_ROWBYTES);
            #pragma unroll
            for (int i = 0; i < 8; ++i)
                gnxt[i] = __hip_atomic_load(&glp[8 * lane + i], __ATOMIC_RELAXED,
                                            __HIP_MEMORY_SCOPE_AGENT);
        }
    }
}

__global__ __launch_bounds__(128, 1) void snn_kernel_p(const float* __restrict__ weight,
                                                       const uint8_t* __restrict__ codeX,
                                                       const uint8_t* __restrict__ codeP,
                                                       uint8_t* __restrict__ slots,
                                                       float* __restrict__ out) {
    const int tid  = threadIdx.x;
    const int wave = tid >> 6;
    const int lane = tid & 63;
    const int row  = blockIdx.x * 2 + wave;    // 512 autonomous waves, 256 CUs

    float wA[CPL], wB[CPL];
    #pragma unroll
    for (int j = 0; j < CPL; ++j) {
        int col = lane * CPL + j;
        float v = (col < CIN) ? weight[row * CIN + col] : 0.0f;
        wA[j] = v; wB[j] = v;
    }

    const uint4* codeX4 = (const uint4*)codeX;
    const uint4* codeP4 = (const uint4*)codeP;

    float xf0[CPL], pf0[CPL], xf1[CPL], pf1[CPL];
    {
        uint4 cx0 = codeX4[lane];
        uint4 cp0 = codeP4[lane];
        decode_planes(cx0, cp0, xf0, pf0);
    }
    uint4 cwxA = codeX4[64 + lane];
    uint4 cwpA = codeP4[64 + lane];
    uint4 cwxB = make_uint4(0u, 0u, 0u, 0u);
    uint4 cwpB = make_uint4(0u, 0u, 0u, 0u);

    unsigned long long gA[8], gB[8];
    #pragma unroll
    for (int i = 0; i < 8; ++i) { gA[i] = 0xB0B0B0B0B0B0B0B0ull; gB[i] = gA[i]; }

    float memA = 0.0f, memB = 0.0f;
    bool  psA = true, psB = true;          // spike(-1)=true quirk
    int p2 = 0, p3 = 0;
    int hb_m1 = 0, hb_m2 = 0;
    bool weq = true;                       // wA==wB at start
    uint32_t myb = 0u;

    for (int u = 0; u < T_STEPS; u += 2) {
        snn_step_p(u,     row, lane, codeX4, codeP4, slots, wA, wB,
                   xf0, pf0, xf1, pf1, cwxA, cwpA, cwxB, cwpB, gA, gB,
                   memA, memB, psA, psB, p2, p3, hb_m1, hb_m2, weq, myb);
        snn_step_p(u + 1, row, lane, codeX4, codeP4, slots, wA, wB,
                   xf1, pf1, xf0, pf0, cwxB, cwpB, cwxA, cwpA, gB, gA,
                   memA, memB, psA, psB, p2, p3, hb_m1, hb_m2, weq, myb);
    }

    // ---- epilogue (verbatim wide) ----
    {
        const int kk = (p3 << 1) | p2;
        int cst;
        if (((hb_m2 >> kk) & 1) != 0) {
            cst = 1;
        } else {
            const unsigned long long* gl2 =
                (const unsigned long long*)(slots + (size_t)(T_STEPS - 2) * W_ROWBYTES);
            unsigned long long g2[8];
            for (;;) {
                #pragma unroll
                for (int i = 0; i < 8; ++i)
                    g2[i] = __hip_atomic_load(&gl2[8 * lane + i],
                                              __ATOMIC_RELAXED,
                                              __HIP_MEMORY_SCOPE_AGENT);
                bool anyset, allp;
                scan8w(g2, kk, anyset, allp);
                if (__any((int)anyset)) { cst = 1; break; }
                if (__all((int)allp)) { cst = 0; break; }
                __builtin_amdgcn_s_sleep(1);
            }
        }
        bool sr = cst ? psB : psA;
        {
            int v = T_STEPS - 1;
            if ((v & 63) == lane) myb |= (sr ? 1u : 0u) << (v >> 6);
        }
        #pragma unroll
        for (int b = 0; b < 16; ++b) {
            int s = b * 64 + lane;
            if (s < T_STEPS)
                out[(size_t)s * COUT + row] = (float)((myb >> b) & 1u);
        }
    }
}

// ======================= narrow fallback (proven r24 narrow) =======================
__device__ __forceinline__ void snn_step_n(
    int u, int row, int lane,
    const uint4* __restrict__ code4, uint8_t* __restrict__ slots,
    float (&wA)[CPL], float (&wB)[CPL],
    float (&xfc)[CPL], float (&pfc)[CPL],
    float (&xfn)[CPL], float (&pfn)[CPL],
    uint4& cwn, uint4& cwl,
    float& memA, float& memB, bool& psA, bool& psB,
    int& p2, int& p3, int& hb_m1, int& hb_m2,
    uint32_t& myb)
{
    cwl = (u + 2 < T_STEPS) ? code4[(size_t)(u + 2) * 64 + lane]
                            : make_uint4(0u, 0u, 0u, 0u);
    const int kk = (p3 << 1) | p2;
    const bool selfdec = (u >= 2) && (((hb_m2 >> kk) & 1) != 0);
    const unsigned long long* gl =
        (const unsigned long long*)(slots + (size_t)(u >= 2 ? u - 2 : 0) * N_NROW);
    unsigned long long gv = 0xB0B0B0B0B0B0B0B0ull;
    if (u >= 2 && !selfdec)
        gv = __hip_atomic_load(&gl[lane], __ATOMIC_RELAXED,
                               __HIP_MEMORY_SCOPE_AGENT);

    float dA = 0.0f, dB = 0.0f;
    #pragma unroll
    for (int j = 0; j < CPL; ++j) { dA += xfc[j] * wA[j]; dB += xfc[j] * wB[j]; }
    float dotA = wave_sum(dA);
    float dotB = wave_sum(dB);

    decode_code(cwn, xfn, pfn);

    float sa = memA + dotA;
    float sb = memB + dotB;
    float m00 = fmaxf(sa, 0.0f), m01 = fmaxf(sa - PROHIB_F, 0.0f);
    float m10 = fmaxf(sb, 0.0f), m11 = fmaxf(sb - PROHIB_F, 0.0f);
    bool s00 = m00 >= VTHR_F, s01 = m01 >= VTHR_F;
    bool s10 = m10 >= VTHR_F, s11 = m11 >= VTHR_F;
    int hb = (s00 ? 1 : 0) | (s01 ? 2 : 0) | (s10 ? 4 : 0) | (s11 ? 8 : 0);

    if (lane == 0)
        __hip_atomic_store(&slots[(size_t)u * N_NROW + row],
                           (uint8_t)(0xB0u | (uint32_t)hb),
                           __ATOMIC_RELAXED, __HIP_MEMORY_SCOPE_AGENT);

    int bst = 0;
    if (u >= 2) {
        if (selfdec) {
            bst = 1;
        } else {
            for (;;) {
                bool anyset, allp;
                scan8(gv, kk, anyset, allp);
                if (__any((int)anyset)) { bst = 1; break; }
                if (__all((int)allp)) { bst = 0; break; }
                __builtin_amdgcn_s_sleep(1);
                gv = __hip_atomic_load(&gl[lane], __ATOMIC_RELAXED,
                                       __HIP_MEMORY_SCOPE_AGENT);
            }
        }
    }
    p3 = p2; p2 = bst;
    hb_m2 = hb_m1; hb_m1 = hb;

    bool sprv = bst ? psB : psA;
    bool sc0  = bst ? s10 : s00;
    bool sc1  = bst ? s11 : s01;
    float mc0 = bst ? m10 : m00;
    float mc1 = bst ? m11 : m01;

    if (u >= 1) {
        int v = u - 1;
        if ((v & 63) == lane) myb |= (sprv ? 1u : 0u) << (v >> 6);
    }

    memA = sc0 ? 0.0f : mc0;
    memB = sc1 ? 0.0f : mc1;

    float s0f = sc0 ? 1.0f : 0.0f;
    float s1f = sc1 ? 1.0f : 0.0f;
    float d0f = (!sc0 && sprv) ? 1.0f : 0.0f;
    float d1f = (!sc1 && sprv) ? 1.0f : 0.0f;
    #pragma unroll
    for (int j = 0; j < CPL; ++j) {
        float base = bst ? wB[j] : wA[j];
        float ta = fminf(fmaf(s0f, pfc[j], base), 127.0f);
        wA[j] = fmaxf(fmaf(-d0f, xfc[j], ta), 0.0f);
        float tb = fminf(fmaf(s1f, pfc[j], base), 127.0f);
        wB[j] = fmaxf(fmaf(-d1f, xfc[j], tb), 0.0f);
    }
    psA = sc0; psB = sc1;
}

__global__ __launch_bounds__(128, 1) void snn_kernel_n(const float* __restrict__ weight,
                                                       const uint8_t* __restrict__ code,
                                                       uint8_t* __restrict__ slots,
                                                       float* __restrict__ out) {
    const int tid  = threadIdx.x;
    const int wave = tid >> 6;
    const int lane = tid & 63;
    const int row  = blockIdx.x * 2 + wave;

    float wA[CPL], wB[CPL];
    #pragma unroll
    for (int j = 0; j < CPL; ++j) {
        int col = lane * CPL + j;
        float v = (col < CIN) ? weight[row * CIN + col] : 0.0f;
        wA[j] = v; wB[j] = v;
    }

    const uint4* code4 = (const uint4*)code;
    float xf0[CPL], pf0[CPL], xf1[CPL], pf1[CPL];
    {
        uint4 c0 = code4[lane];
        decode_code(c0, xf0, pf0);
    }
    uint4 cwA = code4[64 + lane];
    uint4 cwB = make_uint4(0u, 0u, 0u, 0u);

    float memA = 0.0f, memB = 0.0f;
    bool  psA = true, psB = true;
    int p2 = 0, p3 = 0;
    int hb_m1 = 0, hb_m2 = 0;
    uint32_t myb = 0u;

    for (int u = 0; u < T_STEPS; u += 2) {
        snn_step_n(u,     row, lane, code4, slots, wA, wB,
                   xf0, pf0, xf1, pf1, cwA, cwB,
                   memA, memB, psA, psB, p2, p3, hb_m1, hb_m2, myb);
        snn_step_n(u + 1, row, lane, code4, slots, wA, wB,
                   xf1, pf1, xf0, pf0, cwB, cwA,
                   memA, memB, psA, psB, p2, p3, hb_m1, hb_m2, myb);
    }

    {
        const int kk = (p3 << 1) | p2;
        int cst;
        if (((hb_m2 >> kk) & 1) != 0) {
            cst = 1;
        } else {
            const unsigned long long* gl2 =
                (const unsigned long long*)(slots + (size_t)(T_STEPS - 2) * N_NROW);
            unsigned long long gv2;
            for (;;) {
                gv2 = __hip_atomic_load(&gl2[lane], __ATOMIC_RELAXED,
                                        __HIP_MEMORY_SCOPE_AGENT);
                bool anyset, allp;
                scan8(gv2, kk, anyset, allp);
                if (__any((int)anyset)) { cst = 1; break; }
                if (__all((int)allp)) { cst = 0; break; }
                __builtin_amdgcn_s_sleep(1);
            }
        }
        bool sr = cst ? psB : psA;
        {
            int v = T_STEPS - 1;
            if ((v & 63) == lane) myb |= (sr ? 1u : 0u) << (v >> 6);
        }
        #pragma unroll
        for (int b = 0; b < 16; ++b) {
            int s = b * 64 + lane;
            if (s < T_STEPS)
                out[(size_t)s * COUT + row] = (float)((myb >> b) & 1u);
        }
    }
}

extern "C" void kernel_launch(void* const* d_in, const int* in_sizes, int n_in,
                              void* d_out, int out_size, void* d_ws, size_t ws_size,
                              hipStream_t stream) {
    const int*   x      = (const int*)d_in[0];     // (T,1,CIN) int32
    const float* weight = (const float*)d_in[1];   // (COUT,CIN) f32
    float* out = (float*)d_out;                    // (T,1,COUT) f32

    int prep_threads = T_STEPS * 64;
    int prep_blocks = (prep_threads + 255) / 256;
    if (ws_size >= P_TOTAL) {
        uint8_t* slots = (uint8_t*)d_ws;
        uint8_t* codeX = (uint8_t*)d_ws + P_CODEX_OFFSET;
        uint8_t* codeP = (uint8_t*)d_ws + P_CODEP_OFFSET;
        prep_kernel<2><<<prep_blocks, 256, 0, stream>>>(x, codeX, codeP, slots);
        snn_kernel_p<<<256, 128, 0, stream>>>(weight, codeX, codeP, slots, out);
    } else {
        uint8_t* slots = (uint8_t*)d_ws;
        uint8_t* code  = (uint8_t*)d_ws + N_CODE_OFFSET;
        prep_kernel<0><<<prep_blocks, 256, 0, stream>>>(x, code, nullptr, slots);
        snn_kernel_n<<<256, 128, 0, stream>>>(weight, code, slots, out);
    }
}

// Round 18
// 701.487 us; speedup vs baseline: 1.1888x; 1.1888x over previous
//
#include <hip/hip_runtime.h>
#include <stdint.h>

// Net_11587821765063: sequential SNN scan, T=1000 steps.
// Output = spike_out (T,1,COUT) float32 only.
//
// Round 37 (session r17): CHAMPION RESTORE (r34, 651us) + IN-REGISTER SIMD
// DECODE. r36 post-mortem: plane split cut issue (VALU 21.5->14.7%) but
// DOUBLED code fetch (4.9->8.9MB) and added a second exposed load stream ->
// net regression 651->781. Lesson (mirrors r29): issue cuts only pay when
// memory-stream count is held constant. This round keeps the packed layout
// (one code stream) and splits words in registers:
//   xw = w & 0x01010101        (byte j = x_j)
//   pw = (w >> 1) & 0x7F7F7F7F (byte j = p_j; 0x7F mask cancels the
//                               cross-byte bit from the shift)
//   (float)((xw>>8b)&0xFF) -> v_cvt_f32_ubyteN
// Decode 52 -> ~32 insts, values bit-identical, FETCH unchanged.
// Everything else verbatim r34: full-merge fast path (weq && memA==memB &&
// psA==psB -> 2 hypotheses, no collapse, pre-resolve updates), slow path
// r28, protocol (publish 0xB0|hb @8B-stride wide slots, scan8w, retry,
// selfdec, d1 gated gather prefetch), epilogue. Narrow fallback: r24.

#define T_STEPS 1000
#define CIN     784
#define COUT    512
#define CPL     13            // columns per lane (64*13 = 832 >= 784)
#define VTHR_F   12500.0f
#define PROHIB_F 11250.0f

// narrow (proven) layout
#define N_NROW        512                     // 1B per row per step
#define N_CODE_OFFSET 524288                  // 512 KiB >= 512000 B of slots
// wide layout (proven r24/r28): 8B per row per step
#define W_ROWBYTES    4096                    // 512 rows * 8B stride
#define W_CODE_OFFSET 4194304                 // 4 MiB >= 4,096,000 B of slots
#define CODE_BYTES    (T_STEPS * 64 * 16)     // 1,024,000 B
#define W_TOTAL       ((size_t)W_CODE_OFFSET + (size_t)CODE_BYTES)

// ---- prep: zero slots and pack per-(t,lane) 16-byte code slot:
// byte j (j<13) encodes col = lane*13+j: bit0 = x[t][col], bits[2:1] = p.
template <bool WIDE>
__global__ __launch_bounds__(256) void prep_kernel(const int* __restrict__ x,
                                                   uint8_t* __restrict__ code,
                                                   uint8_t* __restrict__ slots) {
    int gid = blockIdx.x * blockDim.x + threadIdx.x;   // one per (t, lane)
    if (gid >= T_STEPS * 64) return;
    if constexpr (WIDE) {
        uint4 z = make_uint4(0u, 0u, 0u, 0u);
        uint4* s4 = (uint4*)slots;                      // 64000 x 64B = 4.096MB
        #pragma unroll
        for (int k = 0; k < 4; ++k) s4[(size_t)gid * 4 + k] = z;
    } else {
        ((uint2*)slots)[gid] = make_uint2(0u, 0u);      // 64000 x 8B
    }
    int t = gid >> 6;
    int lane = gid & 63;
    uint32_t wds[4] = {0u, 0u, 0u, 0u};
    #pragma unroll
    for (int j = 0; j < CPL; ++j) {
        int col = lane * CPL + j;
        uint32_t b = 0u;
        if (col < CIN) {
            int xc = x[t * CIN + col];
            int xp = (t > 0) ? x[(t - 1) * CIN + col] : 0;
            int p = xc ? 2 : ((t == 0) ? 1 : (xp ? 1 : 0));
            b = (uint32_t)((xc & 1) | (p << 1));
        }
        wds[j >> 2] |= b << ((j & 3) * 8);
    }
    ((uint4*)code)[gid] = make_uint4(wds[0], wds[1], wds[2], wds[3]);
}

// narrow scan: 8 row-bytes in one ull
__device__ __forceinline__ void scan8(unsigned long long gv, int kk,
                                      bool& anyset, bool& allp) {
    anyset = false; allp = true;
    #pragma unroll
    for (int i = 0; i < 8; ++i) {
        uint32_t b = (uint32_t)(gv >> (8 * i)) & 0xFFu;
        bool p = (b & 0xF0u) == 0xB0u;
        allp = allp && p;
        anyset = anyset || (p && (((b >> kk) & 1u) != 0u));
    }
}

// wide scan: 8 slots (8B stride), row byte is byte0 of each ull.
__device__ __forceinline__ void scan8w(const unsigned long long* g, int kk,
                                       bool& anyset, bool& allp) {
    anyset = false; allp = true;
    #pragma unroll
    for (int i = 0; i < 8; ++i) {
        uint32_t b = (uint32_t)(g[i] & 0xFFu);
        bool p = (b & 0xF0u) == 0xB0u;
        allp = allp && p;
        anyset = anyset || (p && (((b >> kk) & 1u) != 0u));
    }
}

// in-register SIMD decode: split the packed word into an x-word and a
// p-word, then per-byte v_cvt_f32_ubyteN. Values bit-identical to the
// bfe decode: xw byte j = x_j (only bit0 set); pw byte j = p_j (the 0x7F
// mask cancels the bit carried across byte boundaries by the >>1).
__device__ __forceinline__ void decode_code(const uint4& c, float* xf, float* pf) {
    uint32_t cwd[4] = {c.x, c.y, c.z, c.w};
    #pragma unroll
    for (int w = 0; w < 3; ++w) {
        uint32_t xw = cwd[w] & 0x01010101u;
        uint32_t pw = (cwd[w] >> 1) & 0x7F7F7F7Fu;
        #pragma unroll
        for (int b = 0; b < 4; ++b) {
            xf[w * 4 + b] = (float)((xw >> (b * 8)) & 0xFFu);
            pf[w * 4 + b] = (float)((pw >> (b * 8)) & 0xFFu);
        }
    }
    xf[12] = (float)(cwd[3] & 1u);
    pf[12] = (float)((cwd[3] >> 1) & 0x7Fu);
}

// ---- fast bit-exact butterfly building blocks ----
typedef unsigned uint2ev __attribute__((ext_vector_type(2)));

__device__ __forceinline__ float pl32_sum(float v) {
    unsigned a = __builtin_bit_cast(unsigned, v);
    unsigned b = a;
#if __has_builtin(__builtin_amdgcn_permlane32_swap)
    uint2ev r = __builtin_amdgcn_permlane32_swap(a, b, false, false);
    a = r.x; b = r.y;
#else
    asm volatile("v_permlane32_swap_b32 %0, %1" : "+v"(a), "+v"(b));
#endif
    return __builtin_bit_cast(float, a) + __builtin_bit_cast(float, b);
}

__device__ __forceinline__ float pl16_sum(float v) {
    unsigned a = __builtin_bit_cast(unsigned, v);
    unsigned b = a;
#if __has_builtin(__builtin_amdgcn_permlane16_swap)
    uint2ev r = __builtin_amdgcn_permlane16_swap(a, b, false, false);
    a = r.x; b = r.y;
#else
    asm volatile("v_permlane16_swap_b32 %0, %1" : "+v"(a), "+v"(b));
#endif
    return __builtin_bit_cast(float, a) + __builtin_bit_cast(float, b);
}

template <int CTRL>
__device__ __forceinline__ float dpp_xor_sum(float v) {
    int xi = __builtin_bit_cast(int, v);
    int t = __builtin_amdgcn_update_dpp(xi, xi, CTRL, 0xF, 0xF, false);
    return v + __builtin_bit_cast(float, t);
}

// stage 4 (xor4 within 16-lane rows) in pure DPP (validated r23)
__device__ __forceinline__ float dpp_xor4_sum(float v) {
    int xi = __builtin_bit_cast(int, v);
    int t1 = __builtin_amdgcn_update_dpp(xi, xi, 0x124, 0xF, 0x5, false);
    int t2 = __builtin_amdgcn_update_dpp(t1, xi, 0x12C, 0xF, 0xA, false);
    return v + __builtin_bit_cast(float, t2);
}

// full 64-lane sum, pairing bit-identical to the validated xor butterfly
__device__ __forceinline__ float wave_sum(float v) {
    v = pl32_sum(v);                  // stage 32
    v = pl16_sum(v);                  // stage 16
    v = dpp_xor_sum<0x128>(v);        // stage 8
    v = dpp_xor4_sum(v);              // stage 4
    v = dpp_xor_sum<0x4E>(v);         // stage 2
    v = dpp_xor_sum<0xB1>(v);         // stage 1
    return v;
}

__device__ __forceinline__ int rfl(bool b) {
    return __builtin_amdgcn_readfirstlane((int)b);
}

// ======================= wide step (r34 verbatim + SIMD decode) ===========
__device__ __forceinline__ void snn_step_w(
    int u, int row, int lane,
    const uint4* __restrict__ code4, uint8_t* __restrict__ slots,
    float (&wA)[CPL], float (&wB)[CPL],
    float (&xfc)[CPL], float (&pfc)[CPL],
    float (&xfn)[CPL], float (&pfn)[CPL],
    uint4& cwn, uint4& cwl,
    unsigned long long (&gcur)[8], unsigned long long (&gnxt)[8],
    float& memA, float& memB, bool& psA, bool& psB,
    int& p2, int& p3, int& hb_m1, int& hb_m2,
    bool& weq, uint32_t& myb)
{
    // ---- top-of-step: code load for u+2; selfdec from own history ----
    cwl = (u + 2 < T_STEPS) ? code4[(size_t)(u + 2) * 64 + lane]
                            : make_uint4(0u, 0u, 0u, 0u);
    const int kk = (p3 << 1) | p2;
    const bool selfdec = (u >= 2) && (((hb_m2 >> kk) & 1) != 0);
    const unsigned long long* gl =
        (const unsigned long long*)(slots + (size_t)(u >= 2 ? u - 2 : 0) * W_ROWBYTES);
    // gather for this step was PREFETCHED into gcur at end of step u-1.

    // ---- full-merge fast path (verbatim r34) ----
    const bool fastc = weq && (memA == memB) && (psA == psB);
    if (rfl(fastc)) {
        float dA = 0.0f;
        #pragma unroll
        for (int j = 0; j < CPL; ++j) dA += xfc[j] * wA[j];
        float dotA = wave_sum(dA);

        decode_code(cwn, xfn, pfn);

        float sa = memA + dotA;
        float m00 = fmaxf(sa, 0.0f), m01 = fmaxf(sa - PROHIB_F, 0.0f);
        bool s00 = m00 >= VTHR_F, s01 = m01 >= VTHR_F;
        int hb = (s00 ? 5 : 0) | (s01 ? 10 : 0);   // s10==s00, s11==s01

        if (lane == 0)
            __hip_atomic_store(&slots[(size_t)u * W_ROWBYTES + (size_t)row * 8],
                               (uint8_t)(0xB0u | (uint32_t)hb),
                               __ATOMIC_RELAXED, __HIP_MEMORY_SCOPE_AGENT);

        bool sprv = psA;
        if (u >= 1) {
            int v = u - 1;
            if ((v & 63) == lane) myb |= (sprv ? 1u : 0u) << (v >> 6);
        }
        memA = s00 ? 0.0f : m00;
        memB = s01 ? 0.0f : m01;

        const bool sc_eq = (s00 == s01);
        if (rfl(sc_eq)) {
            if (rfl(s00)) {                       // spike
                #pragma unroll
                for (int j = 0; j < CPL; ++j)
                    wA[j] = fminf(pfc[j] + wA[j], 127.0f);
            } else if (rfl(sprv)) {               // depression
                #pragma unroll
                for (int j = 0; j < CPL; ++j)
                    wA[j] = fmaxf(wA[j] - xfc[j], 0.0f);
            }                                     // else: unchanged
        } else {
            float s0f = s00 ? 1.0f : 0.0f;
            float s1f = s01 ? 1.0f : 0.0f;
            float d0f = (!s00 && sprv) ? 1.0f : 0.0f;
            float d1f = (!s01 && sprv) ? 1.0f : 0.0f;
            #pragma unroll
            for (int j = 0; j < CPL; ++j) {
                float base = wA[j];
                float ta = fminf(fmaf(s0f, pfc[j], base), 127.0f);
                wA[j] = fmaxf(fmaf(-d0f, xfc[j], ta), 0.0f);
                float tb = fminf(fmaf(s1f, pfc[j], base), 127.0f);
                wB[j] = fmaxf(fmaf(-d1f, xfc[j], tb), 0.0f);
            }
        }
        weq = sc_eq;
        psA = s00; psB = s01;

        // resolve bst -- feeds ONLY p2/p3 history (verbatim protocol)
        int bst = 0;
        if (u >= 2) {
            if (selfdec) {
                bst = 1;
            } else {
                bool anyset, allp;
                scan8w(gcur, kk, anyset, allp);
                if (__any((int)anyset)) { bst = 1; }
                else if (__all((int)allp)) { bst = 0; }
                else {
                    for (;;) {
                        __builtin_amdgcn_s_sleep(1);
                        #pragma unroll
                        for (int i = 0; i < 8; ++i)
                            gcur[i] = __hip_atomic_load(&gl[8 * lane + i],
                                                        __ATOMIC_RELAXED,
                                                        __HIP_MEMORY_SCOPE_AGENT);
                        scan8w(gcur, kk, anyset, allp);
                        if (__any((int)anyset)) { bst = 1; break; }
                        if (__all((int)allp)) { bst = 0; break; }
                    }
                }
            }
        }
        p3 = p2; p2 = bst;
        hb_m2 = hb_m1; hb_m1 = hb;

        if (u + 1 < T_STEPS && u >= 1) {
            const int kk2 = (p3 << 1) | p2;
            if (((hb_m2 >> kk2) & 1) == 0) {
                const unsigned long long* glp =
                    (const unsigned long long*)(slots + (size_t)(u - 1) * W_ROWBYTES);
                #pragma unroll
                for (int i = 0; i < 8; ++i)
                    gnxt[i] = __hip_atomic_load(&glp[8 * lane + i],
                                                __ATOMIC_RELAXED,
                                                __HIP_MEMORY_SCOPE_AGENT);
            }
        }
        return;
    }

    // ======================= slow path: r28 verbatim =======================
    float dotA, dotB;
    if (rfl(weq)) {
        float dA = 0.0f;
        #pragma unroll
        for (int j = 0; j < CPL; ++j) dA += xfc[j] * wA[j];
        dotA = wave_sum(dA);
        dotB = dotA;                   // bitwise-identical
    } else {
        float dA = 0.0f, dB = 0.0f;
        #pragma unroll
        for (int j = 0; j < CPL; ++j) {
            dA += xfc[j] * wA[j];
            dB += xfc[j] * wB[j];
        }
        dotA = wave_sum(dA);
        dotB = wave_sum(dB);
    }

    decode_code(cwn, xfn, pfn);

    float sa = memA + dotA;
    float sb = memB + dotB;
    float m00 = fmaxf(sa, 0.0f), m01 = fmaxf(sa - PROHIB_F, 0.0f);
    float m10 = fmaxf(sb, 0.0f), m11 = fmaxf(sb - PROHIB_F, 0.0f);
    bool s00 = m00 >= VTHR_F, s01 = m01 >= VTHR_F;
    bool s10 = m10 >= VTHR_F, s11 = m11 >= VTHR_F;
    int hb = (s00 ? 1 : 0) | (s01 ? 2 : 0) | (s10 ? 4 : 0) | (s11 ? 8 : 0);

    if (lane == 0)
        __hip_atomic_store(&slots[(size_t)u * W_ROWBYTES + (size_t)row * 8],
                           (uint8_t)(0xB0u | (uint32_t)hb),
                           __ATOMIC_RELAXED, __HIP_MEMORY_SCOPE_AGENT);

    int bst = 0;
    if (u >= 2) {
        if (selfdec) {
            bst = 1;
        } else {
            bool anyset, allp;
            scan8w(gcur, kk, anyset, allp);
            if (__any((int)anyset)) { bst = 1; }
            else if (__all((int)allp)) { bst = 0; }
            else {
                for (;;) {
                    __builtin_amdgcn_s_sleep(1);       // backoff (rare path)
                    #pragma unroll
                    for (int i = 0; i < 8; ++i)
                        gcur[i] = __hip_atomic_load(&gl[8 * lane + i],
                                                    __ATOMIC_RELAXED,
                                                    __HIP_MEMORY_SCOPE_AGENT);
                    scan8w(gcur, kk, anyset, allp);
                    if (__any((int)anyset)) { bst = 1; break; }
                    if (__all((int)allp)) { bst = 0; break; }
                }
            }
        }
    }
    p3 = p2; p2 = bst;
    hb_m2 = hb_m1; hb_m1 = hb;

    bool sprv = bst ? psB : psA;
    bool sc0  = bst ? s10 : s00;
    bool sc1  = bst ? s11 : s01;
    float mc0 = bst ? m10 : m00;
    float mc1 = bst ? m11 : m01;

    if (u >= 1) {
        int v = u - 1;
        if ((v & 63) == lane) myb |= (sprv ? 1u : 0u) << (v >> 6);
    }

    memA = sc0 ? 0.0f : mc0;
    memB = sc1 ? 0.0f : mc1;

    const bool sc_eq = (sc0 == sc1);
    if (rfl(weq)) {
        if (rfl(sc_eq)) {
            if (rfl(sc0)) {                       // spike
                #pragma unroll
                for (int j = 0; j < CPL; ++j)
                    wA[j] = fminf(pfc[j] + wA[j], 127.0f);
            } else if (rfl(sprv)) {               // depression
                #pragma unroll
                for (int j = 0; j < CPL; ++j)
                    wA[j] = fmaxf(wA[j] - xfc[j], 0.0f);
            }                                     // else: unchanged
        } else {
            float s0f = sc0 ? 1.0f : 0.0f;
            float s1f = sc1 ? 1.0f : 0.0f;
            float d0f = (!sc0 && sprv) ? 1.0f : 0.0f;
            float d1f = (!sc1 && sprv) ? 1.0f : 0.0f;
            #pragma unroll
            for (int j = 0; j < CPL; ++j) {
                float base = wA[j];
                float ta = fminf(fmaf(s0f, pfc[j], base), 127.0f);
                wA[j] = fmaxf(fmaf(-d0f, xfc[j], ta), 0.0f);
                float tb = fminf(fmaf(s1f, pfc[j], base), 127.0f);
                wB[j] = fmaxf(fmaf(-d1f, xfc[j], tb), 0.0f);
            }
        }
    } else {
        if (rfl(sc_eq)) {
            if (rfl(bst != 0)) {
                if (rfl(sc0)) {
                    #pragma unroll
                    for (int j = 0; j < CPL; ++j)
                        wA[j] = fminf(pfc[j] + wB[j], 127.0f);
                } else if (rfl(sprv)) {
                    #pragma unroll
                    for (int j = 0; j < CPL; ++j)
                        wA[j] = fmaxf(wB[j] - xfc[j], 0.0f);
                } else {
                    #pragma unroll
                    for (int j = 0; j < CPL; ++j)
                        wA[j] = wB[j];
                }
            } else {
                if (rfl(sc0)) {
                    #pragma unroll
                    for (int j = 0; j < CPL; ++j)
                        wA[j] = fminf(pfc[j] + wA[j], 127.0f);
                } else if (rfl(sprv)) {
                    #pragma unroll
                    for (int j = 0; j < CPL; ++j)
                        wA[j] = fmaxf(wA[j] - xfc[j], 0.0f);
                }                                 // else: unchanged
            }
        } else {
            float s0f = sc0 ? 1.0f : 0.0f;
            float s1f = sc1 ? 1.0f : 0.0f;
            float d0f = (!sc0 && sprv) ? 1.0f : 0.0f;
            float d1f = (!sc1 && sprv) ? 1.0f : 0.0f;
            if (rfl(bst != 0)) {
                #pragma unroll
                for (int j = 0; j < CPL; ++j) {
                    float base = wB[j];
                    float ta = fminf(fmaf(s0f, pfc[j], base), 127.0f);
                    wA[j] = fmaxf(fmaf(-d0f, xfc[j], ta), 0.0f);
                    float tb = fminf(fmaf(s1f, pfc[j], base), 127.0f);
                    wB[j] = fmaxf(fmaf(-d1f, xfc[j], tb), 0.0f);
                }
            } else {
                #pragma unroll
                for (int j = 0; j < CPL; ++j) {
                    float base = wA[j];
                    float ta = fminf(fmaf(s0f, pfc[j], base), 127.0f);
                    wA[j] = fmaxf(fmaf(-d0f, xfc[j], ta), 0.0f);
                    float tb = fminf(fmaf(s1f, pfc[j], base), 127.0f);
                    wB[j] = fmaxf(fmaf(-d1f, xfc[j], tb), 0.0f);
                }
            }
        }
    }
    weq = sc_eq;
    psA = sc0; psB = sc1;

    if (u + 1 < T_STEPS && u >= 1) {          // (u+1) >= 2
        const int kk2 = (p3 << 1) | p2;
        if (((hb_m2 >> kk2) & 1) == 0) {
            const unsigned long long* glp =
                (const unsigned long long*)(slots + (size_t)(u - 1) * W_ROWBYTES);
            #pragma unroll
            for (int i = 0; i < 8; ++i)
                gnxt[i] = __hip_atomic_load(&glp[8 * lane + i], __ATOMIC_RELAXED,
                                            __HIP_MEMORY_SCOPE_AGENT);
        }
    }
}

__global__ __launch_bounds__(128, 1) void snn_kernel_w(const float* __restrict__ weight,
                                                       const uint8_t* __restrict__ code,
                                                       uint8_t* __restrict__ slots,
                                                       float* __restrict__ out) {
    const int tid  = threadIdx.x;
    const int wave = tid >> 6;
    const int lane = tid & 63;
    const int row  = blockIdx.x * 2 + wave;    // 512 autonomous waves, 256 CUs

    float wA[CPL], wB[CPL];
    #pragma unroll
    for (int j = 0; j < CPL; ++j) {
        int col = lane * CPL + j;
        float v = (col < CIN) ? weight[row * CIN + col] : 0.0f;
        wA[j] = v; wB[j] = v;
    }

    const uint4* code4 = (const uint4*)code;

    float xf0[CPL], pf0[CPL], xf1[CPL], pf1[CPL];
    {
        uint4 c0 = code4[lane];
        decode_code(c0, xf0, pf0);
    }
    uint4 cwA = code4[64 + lane];
    uint4 cwB = make_uint4(0u, 0u, 0u, 0u);

    unsigned long long gA[8], gB[8];
    #pragma unroll
    for (int i = 0; i < 8; ++i) { gA[i] = 0xB0B0B0B0B0B0B0B0ull; gB[i] = gA[i]; }

    float memA = 0.0f, memB = 0.0f;
    bool  psA = true, psB = true;          // spike(-1)=true quirk
    int p2 = 0, p3 = 0;
    int hb_m1 = 0, hb_m2 = 0;
    bool weq = true;                       // wA==wB at start
    uint32_t myb = 0u;

    for (int u = 0; u < T_STEPS; u += 2) {
        snn_step_w(u,     row, lane, code4, slots, wA, wB,
                   xf0, pf0, xf1, pf1, cwA, cwB, gA, gB,
                   memA, memB, psA, psB, p2, p3, hb_m1, hb_m2, weq, myb);
        snn_step_w(u + 1, row, lane, code4, slots, wA, wB,
                   xf1, pf1, xf0, pf0, cwB, cwA, gB, gA,
                   memA, memB, psA, psB, p2, p3, hb_m1, hb_m2, weq, myb);
    }

    // ---- epilogue (verbatim wide) ----
    {
        const int kk = (p3 << 1) | p2;
        int cst;
        if (((hb_m2 >> kk) & 1) != 0) {
            cst = 1;
        } else {
            const unsigned long long* gl2 =
                (const unsigned long long*)(slots + (size_t)(T_STEPS - 2) * W_ROWBYTES);
            unsigned long long g2[8];
            for (;;) {
                #pragma unroll
                for (int i = 0; i < 8; ++i)
                    g2[i] = __hip_atomic_load(&gl2[8 * lane + i],
                                              __ATOMIC_RELAXED,
                                              __HIP_MEMORY_SCOPE_AGENT);
                bool anyset, allp;
                scan8w(g2, kk, anyset, allp);
                if (__any((int)anyset)) { cst = 1; break; }
                if (__all((int)allp)) { cst = 0; break; }
                __builtin_amdgcn_s_sleep(1);
            }
        }
        bool sr = cst ? psB : psA;
        {
            int v = T_STEPS - 1;
            if ((v & 63) == lane) myb |= (sr ? 1u : 0u) << (v >> 6);
        }
        #pragma unroll
        for (int b = 0; b < 16; ++b) {
            int s = b * 64 + lane;
            if (s < T_STEPS)
                out[(size_t)s * COUT + row] = (float)((myb >> b) & 1u);
        }
    }
}

// ======================= narrow fallback (proven r24 narrow) =======================
__device__ __forceinline__ void snn_step_n(
    int u, int row, int lane,
    const uint4* __restrict__ code4, uint8_t* __restrict__ slots,
    float (&wA)[CPL], float (&wB)[CPL],
    float (&xfc)[CPL], float (&pfc)[CPL],
    float (&xfn)[CPL], float (&pfn)[CPL],
    uint4& cwn, uint4& cwl,
    float& memA, float& memB, bool& psA, bool& psB,
    int& p2, int& p3, int& hb_m1, int& hb_m2,
    uint32_t& myb)
{
    cwl = (u + 2 < T_STEPS) ? code4[(size_t)(u + 2) * 64 + lane]
                            : make_uint4(0u, 0u, 0u, 0u);
    const int kk = (p3 << 1) | p2;
    const bool selfdec = (u >= 2) && (((hb_m2 >> kk) & 1) != 0);
    const unsigned long long* gl =
        (const unsigned long long*)(slots + (size_t)(u >= 2 ? u - 2 : 0) * N_NROW);
    unsigned long long gv = 0xB0B0B0B0B0B0B0B0ull;
    if (u >= 2 && !selfdec)
        gv = __hip_atomic_load(&gl[lane], __ATOMIC_RELAXED,
                               __HIP_MEMORY_SCOPE_AGENT);

    float dA = 0.0f, dB = 0.0f;
    #pragma unroll
    for (int j = 0; j < CPL; ++j) { dA += xfc[j] * wA[j]; dB += xfc[j] * wB[j]; }
    float dotA = wave_sum(dA);
    float dotB = wave_sum(dB);

    decode_code(cwn, xfn, pfn);

    float sa = memA + dotA;
    float sb = memB + dotB;
    float m00 = fmaxf(sa, 0.0f), m01 = fmaxf(sa - PROHIB_F, 0.0f);
    float m10 = fmaxf(sb, 0.0f), m11 = fmaxf(sb - PROHIB_F, 0.0f);
    bool s00 = m00 >= VTHR_F, s01 = m01 >= VTHR_F;
    bool s10 = m10 >= VTHR_F, s11 = m11 >= VTHR_F;
    int hb = (s00 ? 1 : 0) | (s01 ? 2 : 0) | (s10 ? 4 : 0) | (s11 ? 8 : 0);

    if (lane == 0)
        __hip_atomic_store(&slots[(size_t)u * N_NROW + row],
                           (uint8_t)(0xB0u | (uint32_t)hb),
                           __ATOMIC_RELAXED, __HIP_MEMORY_SCOPE_AGENT);

    int bst = 0;
    if (u >= 2) {
        if (selfdec) {
            bst = 1;
        } else {
            for (;;) {
                bool anyset, allp;
                scan8(gv, kk, anyset, allp);
                if (__any((int)anyset)) { bst = 1; break; }
                if (__all((int)allp)) { bst = 0; break; }
                __builtin_amdgcn_s_sleep(1);
                gv = __hip_atomic_load(&gl[lane], __ATOMIC_RELAXED,
                                       __HIP_MEMORY_SCOPE_AGENT);
            }
        }
    }
    p3 = p2; p2 = bst;
    hb_m2 = hb_m1; hb_m1 = hb;

    bool sprv = bst ? psB : psA;
    bool sc0  = bst ? s10 : s00;
    bool sc1  = bst ? s11 : s01;
    float mc0 = bst ? m10 : m00;
    float mc1 = bst ? m11 : m01;

    if (u >= 1) {
        int v = u - 1;
        if ((v & 63) == lane) myb |= (sprv ? 1u : 0u) << (v >> 6);
    }

    memA = sc0 ? 0.0f : mc0;
    memB = sc1 ? 0.0f : mc1;

    float s0f = sc0 ? 1.0f : 0.0f;
    float s1f = sc1 ? 1.0f : 0.0f;
    float d0f = (!sc0 && sprv) ? 1.0f : 0.0f;
    float d1f = (!sc1 && sprv) ? 1.0f : 0.0f;
    #pragma unroll
    for (int j = 0; j < CPL; ++j) {
        float base = bst ? wB[j] : wA[j];
        float ta = fminf(fmaf(s0f, pfc[j], base), 127.0f);
        wA[j] = fmaxf(fmaf(-d0f, xfc[j], ta), 0.0f);
        float tb = fminf(fmaf(s1f, pfc[j], base), 127.0f);
        wB[j] = fmaxf(fmaf(-d1f, xfc[j], tb), 0.0f);
    }
    psA = sc0; psB = sc1;
}

__global__ __launch_bounds__(128, 1) void snn_kernel_n(const float* __restrict__ weight,
                                                       const uint8_t* __restrict__ code,
                                                       uint8_t* __restrict__ slots,
                                                       float* __restrict__ out) {
    const int tid  = threadIdx.x;
    const int wave = tid >> 6;
    const int lane = tid & 63;
    const int row  = blockIdx.x * 2 + wave;

    float wA[CPL], wB[CPL];
    #pragma unroll
    for (int j = 0; j < CPL; ++j) {
        int col = lane * CPL + j;
        float v = (col < CIN) ? weight[row * CIN + col] : 0.0f;
        wA[j] = v; wB[j] = v;
    }

    const uint4* code4 = (const uint4*)code;
    float xf0[CPL], pf0[CPL], xf1[CPL], pf1[CPL];
    {
        uint4 c0 = code4[lane];
        decode_code(c0, xf0, pf0);
    }
    uint4 cwA = code4[64 + lane];
    uint4 cwB = make_uint4(0u, 0u, 0u, 0u);

    float memA = 0.0f, memB = 0.0f;
    bool  psA = true, psB = true;
    int p2 = 0, p3 = 0;
    int hb_m1 = 0, hb_m2 = 0;
    uint32_t myb = 0u;

    for (int u = 0; u < T_STEPS; u += 2) {
        snn_step_n(u,     row, lane, code4, slots, wA, wB,
                   xf0, pf0, xf1, pf1, cwA, cwB,
                   memA, memB, psA, psB, p2, p3, hb_m1, hb_m2, myb);
        snn_step_n(u + 1, row, lane, code4, slots, wA, wB,
                   xf1, pf1, xf0, pf0, cwB, cwA,
                   memA, memB, psA, psB, p2, p3, hb_m1, hb_m2, myb);
    }

    {
        const int kk = (p3 << 1) | p2;
        int cst;
        if (((hb_m2 >> kk) & 1) != 0) {
            cst = 1;
        } else {
            const unsigned long long* gl2 =
                (const unsigned long long*)(slots + (size_t)(T_STEPS - 2) * N_NROW);
            unsigned long long gv2;
            for (;;) {
                gv2 = __hip_atomic_load(&gl2[lane], __ATOMIC_RELAXED,
                                        __HIP_MEMORY_SCOPE_AGENT);
                bool anyset, allp;
                scan8(gv2, kk, anyset, allp);
                if (__any((int)anyset)) { cst = 1; break; }
                if (__all((int)allp)) { cst = 0; break; }
                __builtin_amdgcn_s_sleep(1);
            }
        }
        bool sr = cst ? psB : psA;
        {
            int v = T_STEPS - 1;
            if ((v & 63) == lane) myb |= (sr ? 1u : 0u) << (v >> 6);
        }
        #pragma unroll
        for (int b = 0; b < 16; ++b) {
            int s = b * 64 + lane;
            if (s < T_STEPS)
                out[(size_t)s * COUT + row] = (float)((myb >> b) & 1u);
        }
    }
}

extern "C" void kernel_launch(void* const* d_in, const int* in_sizes, int n_in,
                              void* d_out, int out_size, void* d_ws, size_t ws_size,
                              hipStream_t stream) {
    const int*   x      = (const int*)d_in[0];     // (T,1,CIN) int32
    const float* weight = (const float*)d_in[1];   // (COUT,CIN) f32
    float* out = (float*)d_out;                    // (T,1,COUT) f32

    int prep_threads = T_STEPS * 64;
    int prep_blocks = (prep_threads + 255) / 256;
    if (ws_size >= W_TOTAL) {
        uint8_t* slots = (uint8_t*)d_ws;
        uint8_t* code  = (uint8_t*)d_ws + W_CODE_OFFSET;
        prep_kernel<true><<<prep_blocks, 256, 0, stream>>>(x, code, slots);
        snn_kernel_w<<<256, 128, 0, stream>>>(weight, code, slots, out);
    } else {
        uint8_t* slots = (uint8_t*)d_ws;
        uint8_t* code  = (uint8_t*)d_ws + N_CODE_OFFSET;
        prep_kernel<false><<<prep_blocks, 256, 0, stream>>>(x, code, slots);
        snn_kernel_n<<<256, 128, 0, stream>>>(weight, code, slots, out);
    }
}